// Round 1
// baseline (227.389 us; speedup 1.0000x reference)
//
#include <hip/hip_runtime.h>
#include <stdint.h>

// Swin-3D window attention, fused. B=4096 windows, N=64 tokens, C=96, H=8, hd=12.
// One block per window, 4 waves, bf16 MFMA everywhere, fp32 softmax.
//
// ws layout (bytes):
//   [0, 8388608)            biasmT fp32 [64 w][8 h][64 m][64 r]  (bias+mask, transposed)
//   [8388608, +55296)       wqkv  bf16 [288][96]  (Q rows pre-scaled by hd^-0.5)
//   [8443904, +18432)       wproj bf16 [96][96]

typedef float  f32x4  __attribute__((ext_vector_type(4)));
typedef float  f32x16 __attribute__((ext_vector_type(16)));
typedef short  short8 __attribute__((ext_vector_type(8)));

#define WS_WQKV_OFF  (8388608)
#define WS_WPROJ_OFF (8388608 + 55296)

__device__ __forceinline__ unsigned short f2bf(float f) {
  union { float f; uint32_t u; } v; v.f = f;
  uint32_t u = v.u + 0x7fffu + ((v.u >> 16) & 1u);   // RNE; inputs finite
  return (unsigned short)(u >> 16);
}

__global__ void prep_weights(const float* __restrict__ qkv_w,
                             const float* __restrict__ proj_w,
                             unsigned short* __restrict__ ws16) {
  int tid = blockIdx.x * 256 + threadIdx.x;          // 144 blocks * 256 = 36864 exact
  if (tid < 27648) {
    float v = qkv_w[tid];
    if (tid < 9216) v *= 0.28867513459481288f;       // SCALE folded into Q rows
    ws16[WS_WQKV_OFF / 2 + tid] = f2bf(v);
  } else {
    int t = tid - 27648;                             // < 9216
    ws16[WS_WPROJ_OFF / 2 + t] = f2bf(proj_w[t]);
  }
}

// biasmT[w][h][m][r] = bias_table[relidx(r,m)][h] + mask[w][r][m]
__global__ void prep_biasm(const float* __restrict__ mask,
                           const float* __restrict__ bias_table,
                           float* __restrict__ biasmT) {
  int tid = blockIdx.x * 256 + threadIdx.x;          // 8192 blocks * 256 = 2097152 exact
  int r = tid & 63;
  int m = (tid >> 6) & 63;
  int h = (tid >> 12) & 7;
  int w = tid >> 15;
  int dr = r >> 4, hr = (r >> 2) & 3, wr = r & 3;
  int dm = m >> 4, hm = (m >> 2) & 3, wm = m & 3;
  int idx = (dr - dm + 3) * 49 + (hr - hm + 3) * 7 + (wr - wm + 3);
  biasmT[tid] = bias_table[idx * 8 + h] + mask[(w * 64 + r) * 64 + m];
}

__global__ __launch_bounds__(256) void attn_main(
    const float* __restrict__ x, const float* __restrict__ proj_b,
    const unsigned short* __restrict__ ws16, const float* __restrict__ biasmT,
    float* __restrict__ out) {
  // 128 KiB total LDS -> 1 block/CU
  __shared__ __align__(16) unsigned short xb[64][104];     // X bf16, padded (13.0 KiB)
  __shared__ __align__(16) unsigned short q_s[8][64][24];  // token-major, chans 12..15 zero
  __shared__ __align__(16) unsigned short k_s[8][64][24];
  __shared__ __align__(16) unsigned short v_s[8][16][72];  // chan-major (for PV B-frags)
  __shared__ __align__(16) unsigned short p_s[4][64][72];  // per-wave P
  __shared__ __align__(16) unsigned short o_s[64][104];    // attention out, bf16

  const int tid  = threadIdx.x;
  const int wv   = tid >> 6;
  const int lane = tid & 63;
  const int lo4 = lane & 15, hi4 = lane >> 4;
  const int lo5 = lane & 31, hi5 = lane >> 5;
  const int blk = blockIdx.x;
  const int wmask = blk & 63;

  const unsigned short* wqkv  = ws16 + WS_WQKV_OFF / 2;
  const unsigned short* wproj = ws16 + WS_WPROJ_OFF / 2;

  // --- zero pad chans 12..15 of q_s/k_s (only k<16 is ever read as fragment) ---
  for (int i = tid; i < 512; i += 256) {
    int h = i >> 6, r = i & 63;
    *(uint2*)&q_s[h][r][12] = make_uint2(0u, 0u);
    *(uint2*)&k_s[h][r][12] = make_uint2(0u, 0u);
  }

  // --- stage X (fp32 -> bf16 LDS), fully coalesced float4 loads ---
  {
    const float4* xsrc = (const float4*)(x + (size_t)blk * (64 * 96));
    for (int i = tid; i < 1536; i += 256) {
      float4 v = xsrc[i];
      int t = i / 24, c4 = (i % 24) * 4;
      uint2 pk;
      pk.x = (uint32_t)f2bf(v.x) | ((uint32_t)f2bf(v.y) << 16);
      pk.y = (uint32_t)f2bf(v.z) | ((uint32_t)f2bf(v.w) << 16);
      *(uint2*)&xb[t][c4] = pk;
    }
  }
  __syncthreads();

  // --- GEMM1: QKV = X @ Wqkv^T  (M=64 N=288 K=96), wave = 16-row M-tile ---
  {
    f32x4 acc[18];
#pragma unroll
    for (int nt = 0; nt < 18; ++nt) acc[nt] = (f32x4){0.f, 0.f, 0.f, 0.f};
    const int arow = wv * 16 + lo4;
#pragma unroll
    for (int ks = 0; ks < 3; ++ks) {
      short8 af = *(const short8*)&xb[arow][ks * 32 + hi4 * 8];
#pragma unroll
      for (int nt = 0; nt < 18; ++nt) {
        short8 bf = *(const short8*)&wqkv[(nt * 16 + lo4) * 96 + ks * 32 + hi4 * 8];
        acc[nt] = __builtin_amdgcn_mfma_f32_16x16x32_bf16(af, bf, acc[nt], 0, 0, 0);
      }
    }
    // scatter to per-head Q/K (token-major) and V (chan-major)
#pragma unroll
    for (int nt = 0; nt < 18; ++nt) {
      const int o = nt * 16 + lo4;
      const int rem = o - (nt >= 12 ? 192 : (nt >= 6 ? 96 : 0));
      const int head = rem / 12;
      const int ch = rem - head * 12;
#pragma unroll
      for (int j = 0; j < 4; ++j) {
        const int r = wv * 16 + hi4 * 4 + j;
        unsigned short bv = f2bf(acc[nt][j]);
        if (nt < 6)       q_s[head][r][ch] = bv;
        else if (nt < 12) k_s[head][r][ch] = bv;
        else              v_s[head][ch][r] = bv;
      }
    }
  }
  __syncthreads();

  // --- attention: wave handles heads 2w, 2w+1 (no cross-wave deps inside) ---
  for (int it = 0; it < 2; ++it) {
    const int h = wv * 2 + it;
    const float* bm = biasmT + (size_t)(wmask * 8 + h) * 4096;

    // S^T = K @ Q^T via 32x32x16; C initialized with bias+mask (transposed)
    f32x16 c[2][2];
#pragma unroll
    for (int ti = 0; ti < 2; ++ti)
#pragma unroll
      for (int tj = 0; tj < 2; ++tj)
#pragma unroll
        for (int reg = 0; reg < 16; ++reg) {
          int mrow = (reg & 3) + 8 * (reg >> 2) + 4 * hi5;
          c[ti][tj][reg] = bm[(ti * 32 + mrow) * 64 + tj * 32 + lo5];
        }
#pragma unroll
    for (int ti = 0; ti < 2; ++ti) {
      short8 af = *(const short8*)&k_s[h][ti * 32 + lo5][hi5 * 8];
#pragma unroll
      for (int tj = 0; tj < 2; ++tj) {
        short8 bf = *(const short8*)&q_s[h][tj * 32 + lo5][hi5 * 8];
        c[ti][tj] = __builtin_amdgcn_mfma_f32_32x32x16_bf16(af, bf, c[ti][tj], 0, 0, 0);
      }
    }

    // softmax over m (= D rows): lane holds 32 of 64 m per r; partner is lane^32
#pragma unroll
    for (int tj = 0; tj < 2; ++tj) {
      float mx = -1e30f;
#pragma unroll
      for (int ti = 0; ti < 2; ++ti)
#pragma unroll
        for (int reg = 0; reg < 16; ++reg) mx = fmaxf(mx, c[ti][tj][reg]);
      mx = fmaxf(mx, __shfl_xor(mx, 32));
      float sum = 0.f;
#pragma unroll
      for (int ti = 0; ti < 2; ++ti)
#pragma unroll
        for (int reg = 0; reg < 16; ++reg) {
          float e = __expf(c[ti][tj][reg] - mx);
          c[ti][tj][reg] = e;
          sum += e;
        }
      sum += __shfl_xor(sum, 32);
      float rs = 1.0f / sum;
#pragma unroll
      for (int ti = 0; ti < 2; ++ti)
#pragma unroll
        for (int reg = 0; reg < 16; ++reg) c[ti][tj][reg] *= rs;
    }

    // store P transposed back to row-major [r][m]; reg-quads are m-consecutive -> b64
#pragma unroll
    for (int tj = 0; tj < 2; ++tj) {
      const int r = tj * 32 + lo5;
#pragma unroll
      for (int ti = 0; ti < 2; ++ti)
#pragma unroll
        for (int q4 = 0; q4 < 4; ++q4) {
          uint2 pk;
          pk.x = (uint32_t)f2bf(c[ti][tj][4 * q4 + 0]) |
                 ((uint32_t)f2bf(c[ti][tj][4 * q4 + 1]) << 16);
          pk.y = (uint32_t)f2bf(c[ti][tj][4 * q4 + 2]) |
                 ((uint32_t)f2bf(c[ti][tj][4 * q4 + 3]) << 16);
          *(uint2*)&p_s[wv][r][ti * 32 + 8 * q4 + 4 * hi5] = pk;
        }
    }
    // (within-wave LDS RAW: compiler orders p_s write->read via lgkmcnt)

    // PV: O = P @ V  (M=64, N=16(12 used), K=64) via 16x16x32
    f32x4 oacc[4];
#pragma unroll
    for (int mt = 0; mt < 4; ++mt) oacc[mt] = (f32x4){0.f, 0.f, 0.f, 0.f};
#pragma unroll
    for (int ks = 0; ks < 2; ++ks) {
      short8 bfv = *(const short8*)&v_s[h][lo4][ks * 32 + hi4 * 8];
#pragma unroll
      for (int mt = 0; mt < 4; ++mt) {
        short8 afp = *(const short8*)&p_s[wv][mt * 16 + lo4][ks * 32 + hi4 * 8];
        oacc[mt] = __builtin_amdgcn_mfma_f32_16x16x32_bf16(afp, bfv, oacc[mt], 0, 0, 0);
      }
    }
    if (lo4 < 12) {
#pragma unroll
      for (int mt = 0; mt < 4; ++mt)
#pragma unroll
        for (int j = 0; j < 4; ++j)
          o_s[mt * 16 + hi4 * 4 + j][h * 12 + lo4] = f2bf(oacc[mt][j]);
    }
  }
  __syncthreads();

  // --- GEMM3: OUT = O @ Wproj^T + b  (M=64 N=96 K=96) ---
  {
    f32x4 acc[6];
#pragma unroll
    for (int nt = 0; nt < 6; ++nt) acc[nt] = (f32x4){0.f, 0.f, 0.f, 0.f};
    const int arow = wv * 16 + lo4;
#pragma unroll
    for (int ks = 0; ks < 3; ++ks) {
      short8 af = *(const short8*)&o_s[arow][ks * 32 + hi4 * 8];
#pragma unroll
      for (int nt = 0; nt < 6; ++nt) {
        short8 bf = *(const short8*)&wproj[(nt * 16 + lo4) * 96 + ks * 32 + hi4 * 8];
        acc[nt] = __builtin_amdgcn_mfma_f32_16x16x32_bf16(af, bf, acc[nt], 0, 0, 0);
      }
    }
    float* od = out + (size_t)blk * (64 * 96);
#pragma unroll
    for (int nt = 0; nt < 6; ++nt) {
      float pb = proj_b[nt * 16 + lo4];
#pragma unroll
      for (int j = 0; j < 4; ++j)
        od[(wv * 16 + hi4 * 4 + j) * 96 + nt * 16 + lo4] = acc[nt][j] + pb;
    }
  }
}

extern "C" void kernel_launch(void* const* d_in, const int* in_sizes, int n_in,
                              void* d_out, int out_size, void* d_ws, size_t ws_size,
                              hipStream_t stream) {
  const float* x          = (const float*)d_in[0];
  const float* mask       = (const float*)d_in[1];
  const float* qkv_w      = (const float*)d_in[2];
  const float* proj_w     = (const float*)d_in[3];
  const float* proj_b     = (const float*)d_in[4];
  const float* bias_table = (const float*)d_in[5];

  float* biasmT = (float*)d_ws;
  unsigned short* ws16 = (unsigned short*)d_ws;

  prep_weights<<<144, 256, 0, stream>>>(qkv_w, proj_w, ws16);
  prep_biasm<<<8192, 256, 0, stream>>>(mask, bias_table, biasmT);
  attn_main<<<4096, 256, 0, stream>>>(x, proj_b, ws16, biasmT, (float*)d_out);
}

// Round 2
// 177.866 us; speedup vs baseline: 1.2784x; 1.2784x over previous
//
#include <hip/hip_runtime.h>
#include <stdint.h>

// Swin-3D window attention, fused. B=4096 windows, N=64 tokens, C=96, H=8, hd=12.
// One block per window, 4 waves. R2: 2 blocks/CU (LDS 79 KB), in-register P->PV
// (no p_s LDS roundtrip), float4 bias+mask accumulator init.
//
// ws layout (bytes):
//   [0, 8388608)            biasm fp32 [64 w][8 h][64 q][64 m]  (bias+mask)
//   [8388608, +55296)       wqkv  bf16 [288][96]  (Q rows pre-scaled by hd^-0.5)
//   [8443904, +18432)       wproj bf16 [96][96]

typedef float  f32x4  __attribute__((ext_vector_type(4)));
typedef float  f32x16 __attribute__((ext_vector_type(16)));
typedef short  short8 __attribute__((ext_vector_type(8)));

#define WS_WQKV_OFF  (8388608)
#define WS_WPROJ_OFF (8388608 + 55296)

__device__ __forceinline__ unsigned short f2bf(float f) {
  union { float f; uint32_t u; } v; v.f = f;
  uint32_t u = v.u + 0x7fffu + ((v.u >> 16) & 1u);   // RNE; inputs finite
  return (unsigned short)(u >> 16);
}

__global__ void prep_weights(const float* __restrict__ qkv_w,
                             const float* __restrict__ proj_w,
                             unsigned short* __restrict__ ws16) {
  int tid = blockIdx.x * 256 + threadIdx.x;          // 144 blocks * 256 = 36864 exact
  if (tid < 27648) {
    float v = qkv_w[tid];
    if (tid < 9216) v *= 0.28867513459481288f;       // SCALE folded into Q rows
    ws16[WS_WQKV_OFF / 2 + tid] = f2bf(v);
  } else {
    int t = tid - 27648;                             // < 9216
    ws16[WS_WPROJ_OFF / 2 + t] = f2bf(proj_w[t]);
  }
}

// biasm[w][h][q=r][key=m] = bias_table[relidx(r,m)][h] + mask[w][r][m]
__global__ void prep_biasm(const float* __restrict__ mask,
                           const float* __restrict__ bias_table,
                           float* __restrict__ biasm) {
  int tid = blockIdx.x * 256 + threadIdx.x;          // 8192 blocks * 256 = 2097152 exact
  int m = tid & 63;            // key (inner)
  int r = (tid >> 6) & 63;     // query
  int h = (tid >> 12) & 7;
  int w = tid >> 15;
  int dr = r >> 4, hr = (r >> 2) & 3, wr = r & 3;
  int dm = m >> 4, hm = (m >> 2) & 3, wm = m & 3;
  int idx = (dr - dm + 3) * 49 + (hr - hm + 3) * 7 + (wr - wm + 3);
  biasm[tid] = bias_table[idx * 8 + h] + mask[(w * 64 + r) * 64 + m];
}

__global__ __launch_bounds__(256, 2) void attn_main(
    const float* __restrict__ x, const float* __restrict__ proj_b,
    const unsigned short* __restrict__ ws16, const float* __restrict__ biasm,
    float* __restrict__ out) {
  // 80896 B total LDS -> 2 blocks/CU
  __shared__ __align__(16) unsigned short xo[64][104];     // X bf16 (GEMM1) then O bf16 (GEMM3)
  __shared__ __align__(16) unsigned short q_s[8][64][24];  // token-major, chans 12..15 zero
  __shared__ __align__(16) unsigned short k_s[8][64][24];
  __shared__ __align__(16) unsigned short v_s[8][16][72];  // chan-major

  const int tid  = threadIdx.x;
  const int wv   = tid >> 6;
  const int lane = tid & 63;
  const int lo4 = lane & 15, hi4 = lane >> 4;
  const int lo5 = lane & 31, hi5 = lane >> 5;
  const int blk = blockIdx.x;
  const int wmask = blk & 63;

  const unsigned short* wqkv  = ws16 + WS_WQKV_OFF / 2;
  const unsigned short* wproj = ws16 + WS_WPROJ_OFF / 2;

  // --- zero pad chans 12..15 of q_s/k_s ---
  for (int i = tid; i < 512; i += 256) {
    int h = i >> 6, r = i & 63;
    *(uint2*)&q_s[h][r][12] = make_uint2(0u, 0u);
    *(uint2*)&k_s[h][r][12] = make_uint2(0u, 0u);
  }

  // --- stage X (fp32 -> bf16 LDS), coalesced float4 loads ---
  {
    const float4* xsrc = (const float4*)(x + (size_t)blk * (64 * 96));
    for (int i = tid; i < 1536; i += 256) {
      float4 v = xsrc[i];
      int t = i / 24, c4 = (i % 24) * 4;
      uint2 pk;
      pk.x = (uint32_t)f2bf(v.x) | ((uint32_t)f2bf(v.y) << 16);
      pk.y = (uint32_t)f2bf(v.z) | ((uint32_t)f2bf(v.w) << 16);
      *(uint2*)&xo[t][c4] = pk;
    }
  }
  __syncthreads();

  // --- GEMM1: QKV = X @ Wqkv^T  (M=64 N=288 K=96), wave = 16-row M-tile ---
  {
    f32x4 acc[18];
#pragma unroll
    for (int nt = 0; nt < 18; ++nt) acc[nt] = (f32x4){0.f, 0.f, 0.f, 0.f};
    const int arow = wv * 16 + lo4;
#pragma unroll
    for (int ks = 0; ks < 3; ++ks) {
      short8 af = *(const short8*)&xo[arow][ks * 32 + hi4 * 8];
#pragma unroll
      for (int nt = 0; nt < 18; ++nt) {
        short8 bf = *(const short8*)&wqkv[(nt * 16 + lo4) * 96 + ks * 32 + hi4 * 8];
        acc[nt] = __builtin_amdgcn_mfma_f32_16x16x32_bf16(af, bf, acc[nt], 0, 0, 0);
      }
    }
    // scatter to per-head Q/K (token-major) and V (chan-major)
#pragma unroll
    for (int nt = 0; nt < 18; ++nt) {
      const int o = nt * 16 + lo4;
      const int rem = o - (nt >= 12 ? 192 : (nt >= 6 ? 96 : 0));
      const int head = rem / 12;
      const int ch = rem - head * 12;
#pragma unroll
      for (int j = 0; j < 4; ++j) {
        const int r = wv * 16 + hi4 * 4 + j;
        unsigned short bv = f2bf(acc[nt][j]);
        if (nt < 6)       q_s[head][r][ch] = bv;
        else if (nt < 12) k_s[head][r][ch] = bv;
        else              v_s[head][ch][r] = bv;
      }
    }
  }
  __syncthreads();

  // --- attention: wave handles heads 2w, 2w+1 ---
  for (int it = 0; it < 2; ++it) {
    const int h = wv * 2 + it;
    const float* bm = biasm + (size_t)(wmask * 8 + h) * 4096;

    // S^T = K @ Q^T via 32x32x16; C init from biasm[q][m] (m reg-contiguous -> float4)
    f32x16 c[2][2];
#pragma unroll
    for (int ti = 0; ti < 2; ++ti)
#pragma unroll
      for (int tj = 0; tj < 2; ++tj)
#pragma unroll
        for (int q4 = 0; q4 < 4; ++q4) {
          float4 b4 = *(const float4*)&bm[(tj * 32 + lo5) * 64 + ti * 32 + 8 * q4 + 4 * hi5];
          c[ti][tj][4 * q4 + 0] = b4.x;
          c[ti][tj][4 * q4 + 1] = b4.y;
          c[ti][tj][4 * q4 + 2] = b4.z;
          c[ti][tj][4 * q4 + 3] = b4.w;
        }
#pragma unroll
    for (int ti = 0; ti < 2; ++ti) {
      short8 af = *(const short8*)&k_s[h][ti * 32 + lo5][hi5 * 8];
#pragma unroll
      for (int tj = 0; tj < 2; ++tj) {
        short8 bf = *(const short8*)&q_s[h][tj * 32 + lo5][hi5 * 8];
        c[ti][tj] = __builtin_amdgcn_mfma_f32_32x32x16_bf16(af, bf, c[ti][tj], 0, 0, 0);
      }
    }

    // softmax over m (rows of S^T): lane holds 32 of 64 m per q; partner lane^32
#pragma unroll
    for (int tj = 0; tj < 2; ++tj) {
      float mx = -1e30f;
#pragma unroll
      for (int ti = 0; ti < 2; ++ti)
#pragma unroll
        for (int reg = 0; reg < 16; ++reg) mx = fmaxf(mx, c[ti][tj][reg]);
      mx = fmaxf(mx, __shfl_xor(mx, 32));
      float sum = 0.f;
#pragma unroll
      for (int ti = 0; ti < 2; ++ti)
#pragma unroll
        for (int reg = 0; reg < 16; ++reg) {
          float e = __expf(c[ti][tj][reg] - mx);
          c[ti][tj][reg] = e;
          sum += e;
        }
      sum += __shfl_xor(sum, 32);
      float rs = 1.0f / sum;
#pragma unroll
      for (int ti = 0; ti < 2; ++ti)
#pragma unroll
        for (int reg = 0; reg < 16; ++reg) c[ti][tj][reg] *= rs;
    }

    // pack P^T to bf16 pairs: pk[ti][tj][u] = {reg 2u, reg 2u+1}
    uint32_t pk[2][2][8];
#pragma unroll
    for (int ti = 0; ti < 2; ++ti)
#pragma unroll
      for (int tj = 0; tj < 2; ++tj)
#pragma unroll
        for (int u = 0; u < 8; ++u)
          pk[ti][tj][u] = (uint32_t)f2bf(c[ti][tj][2 * u]) |
                          ((uint32_t)f2bf(c[ti][tj][2 * u + 1]) << 16);

    // PV: O^T = V^T @ P^T via 32x32x16. A = V^T from v_s (rows >= 12 garbage,
    // contained per-row, discarded). B = P^T assembled in-register:
    // needed m = 16*kc + 8*hi5 + 4*jh + r2 ; jh==hi5 -> own quad, else lane^32.
    f32x16 oD[2];
    oD[0] = (f32x16)(0.f); oD[1] = (f32x16)(0.f);
#pragma unroll
    for (int kc = 0; kc < 4; ++kc) {
      const int ti = kc >> 1, base = 4 * (kc & 1);
      short8 av = *(const short8*)&v_s[h][lo5 & 15][kc * 16 + hi5 * 8];
#pragma unroll
      for (int tj = 0; tj < 2; ++tj) {
        uint32_t A0 = pk[ti][tj][base + 0], A1 = pk[ti][tj][base + 1];
        uint32_t A2 = pk[ti][tj][base + 2], A3 = pk[ti][tj][base + 3];
        uint32_t k0 = hi5 ? A2 : A0, k1 = hi5 ? A3 : A1;
        uint32_t s0 = (uint32_t)__shfl_xor((int)(hi5 ? A0 : A2), 32);
        uint32_t s1 = (uint32_t)__shfl_xor((int)(hi5 ? A1 : A3), 32);
        union { uint32_t u[4]; short8 s; } bfr;
        bfr.u[0] = hi5 ? s0 : k0;
        bfr.u[1] = hi5 ? s1 : k1;
        bfr.u[2] = hi5 ? k0 : s0;
        bfr.u[3] = hi5 ? k1 : s1;
        oD[tj] = __builtin_amdgcn_mfma_f32_32x32x16_bf16(av, bfr.s, oD[tj], 0, 0, 0);
      }
    }

    // O^T[c][q]: lane holds q = tj*32+lo5, chans c = r2 + 8*q4 + 4*hi5 in regs
#pragma unroll
    for (int tj = 0; tj < 2; ++tj) {
      const int q = tj * 32 + lo5;
#pragma unroll
      for (int reg = 0; reg < 8; ++reg) {
        const int q4 = reg >> 2, r2 = reg & 3;
        if (q4 == 0) {
          xo[q][h * 12 + r2 + 4 * hi5] = f2bf(oD[tj][reg]);      // c in 0..7
        } else if (hi5 == 0) {
          xo[q][h * 12 + 8 + r2] = f2bf(oD[tj][reg]);            // c in 8..11
        }
      }
    }
  }
  __syncthreads();

  // --- GEMM3: OUT = O @ Wproj^T + b  (M=64 N=96 K=96) ---
  {
    f32x4 acc[6];
#pragma unroll
    for (int nt = 0; nt < 6; ++nt) acc[nt] = (f32x4){0.f, 0.f, 0.f, 0.f};
    const int arow = wv * 16 + lo4;
#pragma unroll
    for (int ks = 0; ks < 3; ++ks) {
      short8 af = *(const short8*)&xo[arow][ks * 32 + hi4 * 8];
#pragma unroll
      for (int nt = 0; nt < 6; ++nt) {
        short8 bf = *(const short8*)&wproj[(nt * 16 + lo4) * 96 + ks * 32 + hi4 * 8];
        acc[nt] = __builtin_amdgcn_mfma_f32_16x16x32_bf16(af, bf, acc[nt], 0, 0, 0);
      }
    }
    float* od = out + (size_t)blk * (64 * 96);
#pragma unroll
    for (int nt = 0; nt < 6; ++nt) {
      float pb = proj_b[nt * 16 + lo4];
#pragma unroll
      for (int j = 0; j < 4; ++j)
        od[(wv * 16 + hi4 * 4 + j) * 96 + nt * 16 + lo4] = acc[nt][j] + pb;
    }
  }
}

extern "C" void kernel_launch(void* const* d_in, const int* in_sizes, int n_in,
                              void* d_out, int out_size, void* d_ws, size_t ws_size,
                              hipStream_t stream) {
  const float* x          = (const float*)d_in[0];
  const float* mask       = (const float*)d_in[1];
  const float* qkv_w      = (const float*)d_in[2];
  const float* proj_w     = (const float*)d_in[3];
  const float* proj_b     = (const float*)d_in[4];
  const float* bias_table = (const float*)d_in[5];

  float* biasm = (float*)d_ws;
  unsigned short* ws16 = (unsigned short*)d_ws;

  prep_weights<<<144, 256, 0, stream>>>(qkv_w, proj_w, ws16);
  prep_biasm<<<8192, 256, 0, stream>>>(mask, bias_table, biasm);
  attn_main<<<4096, 256, 0, stream>>>(x, proj_b, ws16, biasm, (float*)d_out);
}

// Round 3
// 175.415 us; speedup vs baseline: 1.2963x; 1.0140x over previous
//
#include <hip/hip_runtime.h>
#include <stdint.h>

// Swin-3D window attention, fused. B=4096 windows, N=64 tokens, C=96, H=8, hd=12.
// R3: one block per window, 512 threads / 8 waves, ONE head per wave.
// LDS 80896 B -> 2 blocks/CU -> 16 waves/CU (4/SIMD).
//
// ws layout (bytes):
//   [0, 8388608)            biasm fp32 [64 w][8 h][64 q][64 m]  (bias+mask)
//   [8388608, +55296)       wqkv  bf16 [288][96]  (Q rows pre-scaled by hd^-0.5)
//   [8443904, +18432)       wproj bf16 [96][96]

typedef float  f32x4  __attribute__((ext_vector_type(4)));
typedef float  f32x16 __attribute__((ext_vector_type(16)));
typedef short  short8 __attribute__((ext_vector_type(8)));

#define WS_WQKV_OFF  (8388608)
#define WS_WPROJ_OFF (8388608 + 55296)

__device__ __forceinline__ unsigned short f2bf(float f) {
  union { float f; uint32_t u; } v; v.f = f;
  uint32_t u = v.u + 0x7fffu + ((v.u >> 16) & 1u);   // RNE; inputs finite
  return (unsigned short)(u >> 16);
}

__global__ void prep_weights(const float* __restrict__ qkv_w,
                             const float* __restrict__ proj_w,
                             unsigned short* __restrict__ ws16) {
  int tid = blockIdx.x * 256 + threadIdx.x;          // 144 blocks * 256 = 36864 exact
  if (tid < 27648) {
    float v = qkv_w[tid];
    if (tid < 9216) v *= 0.28867513459481288f;       // SCALE folded into Q rows
    ws16[WS_WQKV_OFF / 2 + tid] = f2bf(v);
  } else {
    int t = tid - 27648;                             // < 9216
    ws16[WS_WPROJ_OFF / 2 + t] = f2bf(proj_w[t]);
  }
}

// biasm[w][h][q=r][key=m] = bias_table[relidx(r,m)][h] + mask[w][r][m]
__global__ void prep_biasm(const float* __restrict__ mask,
                           const float* __restrict__ bias_table,
                           float* __restrict__ biasm) {
  int tid = blockIdx.x * 256 + threadIdx.x;          // 8192 blocks * 256 = 2097152 exact
  int m = tid & 63;            // key (inner)
  int r = (tid >> 6) & 63;     // query
  int h = (tid >> 12) & 7;
  int w = tid >> 15;
  int dr = r >> 4, hr = (r >> 2) & 3, wr = r & 3;
  int dm = m >> 4, hm = (m >> 2) & 3, wm = m & 3;
  int idx = (dr - dm + 3) * 49 + (hr - hm + 3) * 7 + (wr - wm + 3);
  biasm[tid] = bias_table[idx * 8 + h] + mask[(w * 64 + r) * 64 + m];
}

__global__ __launch_bounds__(512, 4) void attn_main(
    const float* __restrict__ x, const float* __restrict__ proj_b,
    const unsigned short* __restrict__ ws16, const float* __restrict__ biasm,
    float* __restrict__ out) {
  // 80896 B total LDS -> 2 blocks/CU
  __shared__ __align__(16) unsigned short xo[64][104];     // X bf16 (GEMM1) then O bf16 (GEMM3)
  __shared__ __align__(16) unsigned short q_s[8][64][24];  // token-major, chans 12..15 zero
  __shared__ __align__(16) unsigned short k_s[8][64][24];
  __shared__ __align__(16) unsigned short v_s[8][16][72];  // chan-major

  const int tid  = threadIdx.x;
  const int wv   = tid >> 6;          // 0..7
  const int lane = tid & 63;
  const int lo4 = lane & 15, hi4 = lane >> 4;
  const int lo5 = lane & 31, hi5 = lane >> 5;
  const int blk = blockIdx.x;
  const int wmask = blk & 63;

  const unsigned short* wqkv  = ws16 + WS_WQKV_OFF / 2;
  const unsigned short* wproj = ws16 + WS_WPROJ_OFF / 2;

  // --- zero pad chans 12..15 of q_s/k_s (512 threads -> one shot) ---
  {
    int h = tid >> 6, r = tid & 63;
    *(uint2*)&q_s[h][r][12] = make_uint2(0u, 0u);
    *(uint2*)&k_s[h][r][12] = make_uint2(0u, 0u);
  }

  // --- stage X (fp32 -> bf16 LDS), coalesced float4 loads ---
  {
    const float4* xsrc = (const float4*)(x + (size_t)blk * (64 * 96));
    for (int i = tid; i < 1536; i += 512) {
      float4 v = xsrc[i];
      int t = i / 24, c4 = (i % 24) * 4;
      uint2 pk;
      pk.x = (uint32_t)f2bf(v.x) | ((uint32_t)f2bf(v.y) << 16);
      pk.y = (uint32_t)f2bf(v.z) | ((uint32_t)f2bf(v.w) << 16);
      *(uint2*)&xo[t][c4] = pk;
    }
  }
  __syncthreads();

  // --- GEMM1: QKV = X @ Wqkv^T (M=64 N=288 K=96); wave = (M-tile, 9 N-tiles) ---
  {
    const int mt = wv & 3;            // M-tile 0..3
    const int ng = wv >> 2;           // N-group 0..1 (9 tiles each)
    f32x4 acc[9];
#pragma unroll
    for (int nt = 0; nt < 9; ++nt) acc[nt] = (f32x4){0.f, 0.f, 0.f, 0.f};
    const int arow = mt * 16 + lo4;
#pragma unroll
    for (int ks = 0; ks < 3; ++ks) {
      short8 af = *(const short8*)&xo[arow][ks * 32 + hi4 * 8];
#pragma unroll
      for (int nt = 0; nt < 9; ++nt) {
        const int ntg = ng * 9 + nt;
        short8 bf = *(const short8*)&wqkv[(ntg * 16 + lo4) * 96 + ks * 32 + hi4 * 8];
        acc[nt] = __builtin_amdgcn_mfma_f32_16x16x32_bf16(af, bf, acc[nt], 0, 0, 0);
      }
    }
    // scatter to per-head Q/K (token-major) and V (chan-major)
#pragma unroll
    for (int nt = 0; nt < 9; ++nt) {
      const int o = (ng * 9 + nt) * 16 + lo4;           // 0..287
      const int rem = o - (o >= 192 ? 192 : (o >= 96 ? 96 : 0));
      const int head = rem / 12;
      const int ch = rem - head * 12;
#pragma unroll
      for (int j = 0; j < 4; ++j) {
        const int r = mt * 16 + hi4 * 4 + j;
        unsigned short bv = f2bf(acc[nt][j]);
        if (o < 96)        q_s[head][r][ch] = bv;
        else if (o < 192)  k_s[head][r][ch] = bv;
        else               v_s[head][ch][r] = bv;
      }
    }
  }
  __syncthreads();

  // --- attention: wave wv handles head wv ---
  {
    const int h = wv;
    const float* bm = biasm + (size_t)(wmask * 8 + h) * 4096;

    // S^T = K @ Q^T via 32x32x16; C init from biasm[q][m] (m reg-contiguous -> float4)
    f32x16 c[2][2];
#pragma unroll
    for (int ti = 0; ti < 2; ++ti)
#pragma unroll
      for (int tj = 0; tj < 2; ++tj)
#pragma unroll
        for (int q4 = 0; q4 < 4; ++q4) {
          float4 b4 = *(const float4*)&bm[(tj * 32 + lo5) * 64 + ti * 32 + 8 * q4 + 4 * hi5];
          c[ti][tj][4 * q4 + 0] = b4.x;
          c[ti][tj][4 * q4 + 1] = b4.y;
          c[ti][tj][4 * q4 + 2] = b4.z;
          c[ti][tj][4 * q4 + 3] = b4.w;
        }
#pragma unroll
    for (int ti = 0; ti < 2; ++ti) {
      short8 af = *(const short8*)&k_s[h][ti * 32 + lo5][hi5 * 8];
#pragma unroll
      for (int tj = 0; tj < 2; ++tj) {
        short8 bf = *(const short8*)&q_s[h][tj * 32 + lo5][hi5 * 8];
        c[ti][tj] = __builtin_amdgcn_mfma_f32_32x32x16_bf16(af, bf, c[ti][tj], 0, 0, 0);
      }
    }

    // softmax over m (rows of S^T): lane holds 32 of 64 m per q; partner lane^32
#pragma unroll
    for (int tj = 0; tj < 2; ++tj) {
      float mx = -1e30f;
#pragma unroll
      for (int ti = 0; ti < 2; ++ti)
#pragma unroll
        for (int reg = 0; reg < 16; ++reg) mx = fmaxf(mx, c[ti][tj][reg]);
      mx = fmaxf(mx, __shfl_xor(mx, 32));
      float sum = 0.f;
#pragma unroll
      for (int ti = 0; ti < 2; ++ti)
#pragma unroll
        for (int reg = 0; reg < 16; ++reg) {
          float e = __expf(c[ti][tj][reg] - mx);
          c[ti][tj][reg] = e;
          sum += e;
        }
      sum += __shfl_xor(sum, 32);
      float rs = 1.0f / sum;
#pragma unroll
      for (int ti = 0; ti < 2; ++ti)
#pragma unroll
        for (int reg = 0; reg < 16; ++reg) c[ti][tj][reg] *= rs;
    }

    // pack P^T to bf16 pairs: pk[ti][tj][u] = {reg 2u, reg 2u+1}
    uint32_t pk[2][2][8];
#pragma unroll
    for (int ti = 0; ti < 2; ++ti)
#pragma unroll
      for (int tj = 0; tj < 2; ++tj)
#pragma unroll
        for (int u = 0; u < 8; ++u)
          pk[ti][tj][u] = (uint32_t)f2bf(c[ti][tj][2 * u]) |
                          ((uint32_t)f2bf(c[ti][tj][2 * u + 1]) << 16);

    // PV: O^T = V^T @ P^T via 32x32x16. A = V^T from v_s (rows >= 12 garbage,
    // contained per-row, discarded). B = P^T assembled in-register:
    // needed m = 16*kc + 8*hi5 + 4*jh + r2 ; jh==hi5 -> own quad, else lane^32.
    f32x16 oD[2];
    oD[0] = (f32x16)(0.f); oD[1] = (f32x16)(0.f);
#pragma unroll
    for (int kc = 0; kc < 4; ++kc) {
      const int ti = kc >> 1, base = 4 * (kc & 1);
      short8 av = *(const short8*)&v_s[h][lo5 & 15][kc * 16 + hi5 * 8];
#pragma unroll
      for (int tj = 0; tj < 2; ++tj) {
        uint32_t A0 = pk[ti][tj][base + 0], A1 = pk[ti][tj][base + 1];
        uint32_t A2 = pk[ti][tj][base + 2], A3 = pk[ti][tj][base + 3];
        uint32_t k0 = hi5 ? A2 : A0, k1 = hi5 ? A3 : A1;
        uint32_t s0 = (uint32_t)__shfl_xor((int)(hi5 ? A0 : A2), 32);
        uint32_t s1 = (uint32_t)__shfl_xor((int)(hi5 ? A1 : A3), 32);
        union { uint32_t u[4]; short8 s; } bfr;
        bfr.u[0] = hi5 ? s0 : k0;
        bfr.u[1] = hi5 ? s1 : k1;
        bfr.u[2] = hi5 ? k0 : s0;
        bfr.u[3] = hi5 ? k1 : s1;
        oD[tj] = __builtin_amdgcn_mfma_f32_32x32x16_bf16(av, bfr.s, oD[tj], 0, 0, 0);
      }
    }

    // O^T[c][q]: lane holds q = tj*32+lo5, chans c = r2 + 8*q4 + 4*hi5 in regs
#pragma unroll
    for (int tj = 0; tj < 2; ++tj) {
      const int q = tj * 32 + lo5;
#pragma unroll
      for (int reg = 0; reg < 8; ++reg) {
        const int q4 = reg >> 2, r2 = reg & 3;
        if (q4 == 0) {
          xo[q][h * 12 + r2 + 4 * hi5] = f2bf(oD[tj][reg]);      // c in 0..7
        } else if (hi5 == 0) {
          xo[q][h * 12 + 8 + r2] = f2bf(oD[tj][reg]);            // c in 8..11
        }
      }
    }
  }
  __syncthreads();

  // --- GEMM3: OUT = O @ Wproj^T + b (M=64 N=96 K=96); wave = (M-tile, 3 N-tiles) ---
  {
    const int mt = wv >> 1;           // M-tile 0..3
    const int nb = (wv & 1) * 3;      // first N-tile (0 or 3)
    f32x4 acc[3];
#pragma unroll
    for (int nt = 0; nt < 3; ++nt) acc[nt] = (f32x4){0.f, 0.f, 0.f, 0.f};
    const int arow = mt * 16 + lo4;
#pragma unroll
    for (int ks = 0; ks < 3; ++ks) {
      short8 af = *(const short8*)&xo[arow][ks * 32 + hi4 * 8];
#pragma unroll
      for (int nt = 0; nt < 3; ++nt) {
        const int ntg = nb + nt;
        short8 bf = *(const short8*)&wproj[(ntg * 16 + lo4) * 96 + ks * 32 + hi4 * 8];
        acc[nt] = __builtin_amdgcn_mfma_f32_16x16x32_bf16(af, bf, acc[nt], 0, 0, 0);
      }
    }
    float* od = out + (size_t)blk * (64 * 96);
#pragma unroll
    for (int nt = 0; nt < 3; ++nt) {
      const int ntg = nb + nt;
      float pb = proj_b[ntg * 16 + lo4];
#pragma unroll
      for (int j = 0; j < 4; ++j)
        od[(mt * 16 + hi4 * 4 + j) * 96 + ntg * 16 + lo4] = acc[nt][j] + pb;
    }
  }
}

extern "C" void kernel_launch(void* const* d_in, const int* in_sizes, int n_in,
                              void* d_out, int out_size, void* d_ws, size_t ws_size,
                              hipStream_t stream) {
  const float* x          = (const float*)d_in[0];
  const float* mask       = (const float*)d_in[1];
  const float* qkv_w      = (const float*)d_in[2];
  const float* proj_w     = (const float*)d_in[3];
  const float* proj_b     = (const float*)d_in[4];
  const float* bias_table = (const float*)d_in[5];

  float* biasm = (float*)d_ws;
  unsigned short* ws16 = (unsigned short*)d_ws;

  prep_weights<<<144, 256, 0, stream>>>(qkv_w, proj_w, ws16);
  prep_biasm<<<8192, 256, 0, stream>>>(mask, bias_table, biasm);
  attn_main<<<4096, 512, 0, stream>>>(x, proj_b, ws16, biasm, (float*)d_out);
}